// Round 1
// baseline (48.973 us; speedup 1.0000x reference)
//
#include <hip/hip_runtime.h>
#include <math.h>

struct F3 { float x, y, z; };

__device__ __forceinline__ F3 f3(float x, float y, float z) { return {x, y, z}; }
__device__ __forceinline__ F3 add(F3 a, F3 b) { return {a.x+b.x, a.y+b.y, a.z+b.z}; }
__device__ __forceinline__ F3 sub(F3 a, F3 b) { return {a.x-b.x, a.y-b.y, a.z-b.z}; }
__device__ __forceinline__ F3 mul(F3 a, float s) { return {a.x*s, a.y*s, a.z*s}; }
__device__ __forceinline__ float dot3(F3 a, F3 b) { return a.x*b.x + a.y*b.y + a.z*b.z; }
__device__ __forceinline__ F3 cross3(F3 a, F3 b) {
    return {a.y*b.z - a.z*b.y, a.z*b.x - a.x*b.z, a.x*b.y - a.y*b.x};
}
// reference _safe_normalize: x * rsqrt(clip(sum(x*x), 1e-20))
__device__ __forceinline__ F3 safe_normalize(F3 a) {
    float d = dot3(a, a);
    float inv = rsqrtf(fmaxf(d, 1e-20f));
    return mul(a, inv);
}

#define BLK 256

__global__ __launch_bounds__(BLK) void gauss_fused_kernel(
    const float* __restrict__ verts,     // (V,3)
    const int*   __restrict__ faces,     // (F,3)
    const int*   __restrict__ binding,   // (N,)
    const float* __restrict__ xyz,       // (N,3)
    const float* __restrict__ rot,       // (N,4)
    const float* __restrict__ scal,      // (N,3)
    const float* __restrict__ opac,      // (N,1)
    const float* __restrict__ fdc,       // (N,1,3)
    float*       __restrict__ out,       // (N,13)
    int N)
{
    __shared__ float sout[BLK * 13];

    const int tid = threadIdx.x;
    const int i  = blockIdx.x * BLK + tid;
    const int count = min(BLK, N - blockIdx.x * BLK);

    if (i < N) {
        // ---- gather face geometry (faces/verts are L2-resident) ----
        const int b = binding[i];
        const int f0 = faces[3*b+0], f1 = faces[3*b+1], f2 = faces[3*b+2];
        const F3 v0 = f3(verts[3*f0], verts[3*f0+1], verts[3*f0+2]);
        const F3 v1 = f3(verts[3*f1], verts[3*f1+1], verts[3*f1+2]);
        const F3 v2 = f3(verts[3*f2], verts[3*f2+1], verts[3*f2+2]);

        const F3 fc  = mul(add(add(v0, v1), v2), (1.0f/3.0f));
        const F3 e01 = sub(v1, v0);
        const F3 e02 = sub(v2, v0);
        const F3 a0 = safe_normalize(e01);
        const F3 a1 = safe_normalize(cross3(a0, e02));
        const F3 a2 = mul(safe_normalize(cross3(a1, a0)), -1.0f);
        const float s0 = sqrtf(dot3(e01, e01));
        const float s1 = fabsf(dot3(a2, e02));
        const float fs = 0.5f * (s0 + s1);

        // ---- per-gaussian inputs ----
        const float px = xyz[3*i+0], py = xyz[3*i+1], pz = xyz[3*i+2];
        const float4 q4 = reinterpret_cast<const float4*>(rot)[i];
        const float sc0 = scal[3*i+0], sc1 = scal[3*i+1], sc2 = scal[3*i+2];
        const float opa = opac[i];
        const float d0 = fdc[3*i+0], d1 = fdc[3*i+1], d2 = fdc[3*i+2];

        // ---- xyz_out = (a0*px + a1*py + a2*pz) * fs + fc ----
        F3 xo = add(add(mul(a0, px), mul(a1, py)), mul(a2, pz));
        xo = add(mul(xo, fs), fc);

        // ---- quaternion -> rotmat Q ----
        const float qn = sqrtf(q4.x*q4.x + q4.y*q4.y + q4.z*q4.z + q4.w*q4.w) + 1e-12f;
        const float qinv = 1.0f / qn;
        const float w = q4.x*qinv, x = q4.y*qinv, y = q4.z*qinv, z = q4.w*qinv;
        const float Q00 = 1.0f - 2.0f*(y*y + z*z);
        const float Q01 = 2.0f*(x*y - z*w);
        const float Q02 = 2.0f*(x*z + y*w);
        const float Q10 = 2.0f*(x*y + z*w);
        const float Q11 = 1.0f - 2.0f*(x*x + z*z);
        const float Q12 = 2.0f*(y*z - x*w);
        const float Q20 = 2.0f*(x*z - y*w);
        const float Q21 = 2.0f*(y*z + x*w);
        const float Q22 = 1.0f - 2.0f*(x*x + y*y);

        // ---- M = O*Q, columns m_k = a0*Q0k + a1*Q1k + a2*Q2k ----
        const F3 m0 = add(add(mul(a0, Q00), mul(a1, Q10)), mul(a2, Q20));
        const F3 m1 = add(add(mul(a0, Q01), mul(a1, Q11)), mul(a2, Q21));
        const F3 m2 = add(add(mul(a0, Q02), mul(a1, Q12)), mul(a2, Q22));

        // ---- scales^2 ----
        const float w0 = expf(sc0) * fs;
        const float w1 = expf(sc1) * fs;
        const float w2 = expf(sc2) * fs;
        const float t0 = w0*w0, t1 = w1*w1, t2 = w2*w2;

        // ---- C = t0*m0 m0^T + t1*m1 m1^T + t2*m2 m2^T ----
        const float C00 = t0*m0.x*m0.x + t1*m1.x*m1.x + t2*m2.x*m2.x;
        const float C01 = t0*m0.x*m0.y + t1*m1.x*m1.y + t2*m2.x*m2.y;
        const float C02 = t0*m0.x*m0.z + t1*m1.x*m1.z + t2*m2.x*m2.z;
        const float C11 = t0*m0.y*m0.y + t1*m1.y*m1.y + t2*m2.y*m2.y;
        const float C12 = t0*m0.y*m0.z + t1*m1.y*m1.z + t2*m2.y*m2.z;
        const float C22 = t0*m0.z*m0.z + t1*m1.z*m1.z + t2*m2.z*m2.z;

        // ---- color ----
        const float sg = 1.0f / (1.0f + expf(-opa));
        const float c0 = fminf(fmaxf((0.5f + 0.282f*d0) * 255.0f, 0.0f), 255.0f);
        const float c1 = fminf(fmaxf((0.5f + 0.282f*d1) * 255.0f, 0.0f), 255.0f);
        const float c2 = fminf(fmaxf((0.5f + 0.282f*d2) * 255.0f, 0.0f), 255.0f);
        const float c3 = fminf(fmaxf(sg * 255.0f, 0.0f), 255.0f);

        // ---- stage row into LDS (stride 13 words: 2-way bank aliasing, free) ----
        float r[13] = {xo.x, xo.y, xo.z, c0, c1, c2, c3, C00, C01, C02, C11, C12, C22};
        #pragma unroll
        for (int j = 0; j < 13; ++j) sout[tid*13 + j] = r[j];
    }

    __syncthreads();

    // ---- coalesced float4 flush of the block's contiguous output span ----
    const int total = count * 13;                       // floats this block writes
    const size_t base = (size_t)blockIdx.x * (BLK * 13);
    const int n4 = total >> 2;
    const float4* s4 = reinterpret_cast<const float4*>(sout);
    float4* o4 = reinterpret_cast<float4*>(out + base); // base*4 bytes % 16 == 0
    for (int j = tid; j < n4; j += BLK) o4[j] = s4[j];
    for (int j = (n4 << 2) + tid; j < total; j += BLK) out[base + j] = sout[j];
}

extern "C" void kernel_launch(void* const* d_in, const int* in_sizes, int n_in,
                              void* d_out, int out_size, void* d_ws, size_t ws_size,
                              hipStream_t stream) {
    const float* verts   = (const float*)d_in[0];
    const int*   faces   = (const int*)  d_in[1];
    const int*   binding = (const int*)  d_in[2];
    const float* xyz     = (const float*)d_in[3];
    const float* rot     = (const float*)d_in[4];
    const float* scal    = (const float*)d_in[5];
    const float* opac    = (const float*)d_in[6];
    const float* fdc     = (const float*)d_in[7];
    // d_in[8] = features_rest: unused by the reference output
    float* out = (float*)d_out;
    const int N = in_sizes[2];

    const int blocks = (N + BLK - 1) / BLK;
    gauss_fused_kernel<<<blocks, BLK, 0, stream>>>(
        verts, faces, binding, xyz, rot, scal, opac, fdc, out, N);
}

// Round 2
// 45.020 us; speedup vs baseline: 1.0878x; 1.0878x over previous
//
#include <hip/hip_runtime.h>
#include <math.h>

struct F3 { float x, y, z; };

__device__ __forceinline__ F3 f3(float x, float y, float z) { return {x, y, z}; }
__device__ __forceinline__ F3 add(F3 a, F3 b) { return {a.x+b.x, a.y+b.y, a.z+b.z}; }
__device__ __forceinline__ F3 sub(F3 a, F3 b) { return {a.x-b.x, a.y-b.y, a.z-b.z}; }
__device__ __forceinline__ F3 mul(F3 a, float s) { return {a.x*s, a.y*s, a.z*s}; }
__device__ __forceinline__ float dot3(F3 a, F3 b) { return a.x*b.x + a.y*b.y + a.z*b.z; }
__device__ __forceinline__ F3 cross3(F3 a, F3 b) {
    return {a.y*b.z - a.z*b.y, a.z*b.x - a.x*b.z, a.x*b.y - a.y*b.x};
}
// reference _safe_normalize: x * rsqrt(clip(sum(x*x), 1e-20))
__device__ __forceinline__ F3 safe_normalize(F3 a) {
    float d = dot3(a, a);
    float inv = rsqrtf(fmaxf(d, 1e-20f));
    return mul(a, inv);
}

#define BLK 256

// ---------------------------------------------------------------------------
// Kernel 1: per-face geometry -> packed 64B/face table in d_ws
//   tab[4f+0] = {fc.x, fc.y, fc.z, fs}
//   tab[4f+1] = {a0.x, a0.y, a0.z, 0}
//   tab[4f+2] = {a1.x, a1.y, a1.z, 0}
//   tab[4f+3] = {a2.x, a2.y, a2.z, 0}
// ---------------------------------------------------------------------------
__global__ __launch_bounds__(BLK) void face_precompute_kernel(
    const float* __restrict__ verts, const int* __restrict__ faces,
    float4* __restrict__ tab, int F)
{
    const int f = blockIdx.x * BLK + threadIdx.x;
    if (f >= F) return;
    const int f0 = faces[3*f+0], f1 = faces[3*f+1], f2 = faces[3*f+2];
    const F3 v0 = f3(verts[3*f0], verts[3*f0+1], verts[3*f0+2]);
    const F3 v1 = f3(verts[3*f1], verts[3*f1+1], verts[3*f1+2]);
    const F3 v2 = f3(verts[3*f2], verts[3*f2+1], verts[3*f2+2]);

    const F3 fc  = mul(add(add(v0, v1), v2), (1.0f/3.0f));
    const F3 e01 = sub(v1, v0);
    const F3 e02 = sub(v2, v0);
    const F3 a0 = safe_normalize(e01);
    const F3 a1 = safe_normalize(cross3(a0, e02));
    const F3 a2 = mul(safe_normalize(cross3(a1, a0)), -1.0f);
    const float s0 = sqrtf(dot3(e01, e01));
    const float s1 = fabsf(dot3(a2, e02));
    const float fs = 0.5f * (s0 + s1);

    tab[4*f+0] = make_float4(fc.x, fc.y, fc.z, fs);
    tab[4*f+1] = make_float4(a0.x, a0.y, a0.z, 0.0f);
    tab[4*f+2] = make_float4(a1.x, a1.y, a1.z, 0.0f);
    tab[4*f+3] = make_float4(a2.x, a2.y, a2.z, 0.0f);
}

// ---------------------------------------------------------------------------
// Kernel 2: per-gaussian map; single-level gather of one 64B line per point
// ---------------------------------------------------------------------------
__global__ __launch_bounds__(BLK) void gauss_main_kernel(
    const float4* __restrict__ tab,      // (F,4) float4
    const int*    __restrict__ binding,  // (N,)
    const float*  __restrict__ xyz,      // (N,3)
    const float*  __restrict__ rot,      // (N,4)
    const float*  __restrict__ scal,     // (N,3)
    const float*  __restrict__ opac,     // (N,1)
    const float*  __restrict__ fdc,      // (N,1,3)
    float*        __restrict__ out,      // (N,13)
    int N)
{
    __shared__ float sout[BLK * 13];

    const int tid = threadIdx.x;
    const int i  = blockIdx.x * BLK + tid;
    const int count = min(BLK, N - blockIdx.x * BLK);

    if (i < N) {
        const int b = binding[i];
        const float4 t0 = tab[4*b+0];
        const float4 t1 = tab[4*b+1];
        const float4 t2 = tab[4*b+2];
        const float4 t3 = tab[4*b+3];
        const F3 fc = f3(t0.x, t0.y, t0.z);
        const float fs = t0.w;
        const F3 a0 = f3(t1.x, t1.y, t1.z);
        const F3 a1 = f3(t2.x, t2.y, t2.z);
        const F3 a2 = f3(t3.x, t3.y, t3.z);

        // ---- per-gaussian inputs ----
        const float px = xyz[3*i+0], py = xyz[3*i+1], pz = xyz[3*i+2];
        const float4 q4 = reinterpret_cast<const float4*>(rot)[i];
        const float sc0 = scal[3*i+0], sc1 = scal[3*i+1], sc2 = scal[3*i+2];
        const float opa = opac[i];
        const float d0 = fdc[3*i+0], d1 = fdc[3*i+1], d2 = fdc[3*i+2];

        // ---- xyz_out = (a0*px + a1*py + a2*pz) * fs + fc ----
        F3 xo = add(add(mul(a0, px), mul(a1, py)), mul(a2, pz));
        xo = add(mul(xo, fs), fc);

        // ---- quaternion -> rotmat Q ----
        const float qn = sqrtf(q4.x*q4.x + q4.y*q4.y + q4.z*q4.z + q4.w*q4.w) + 1e-12f;
        const float qinv = 1.0f / qn;
        const float w = q4.x*qinv, x = q4.y*qinv, y = q4.z*qinv, z = q4.w*qinv;
        const float Q00 = 1.0f - 2.0f*(y*y + z*z);
        const float Q01 = 2.0f*(x*y - z*w);
        const float Q02 = 2.0f*(x*z + y*w);
        const float Q10 = 2.0f*(x*y + z*w);
        const float Q11 = 1.0f - 2.0f*(x*x + z*z);
        const float Q12 = 2.0f*(y*z - x*w);
        const float Q20 = 2.0f*(x*z - y*w);
        const float Q21 = 2.0f*(y*z + x*w);
        const float Q22 = 1.0f - 2.0f*(x*x + y*y);

        // ---- M = O*Q, columns m_k = a0*Q0k + a1*Q1k + a2*Q2k ----
        const F3 m0 = add(add(mul(a0, Q00), mul(a1, Q10)), mul(a2, Q20));
        const F3 m1 = add(add(mul(a0, Q01), mul(a1, Q11)), mul(a2, Q21));
        const F3 m2 = add(add(mul(a0, Q02), mul(a1, Q12)), mul(a2, Q22));

        // ---- scales^2 ----
        const float w0 = expf(sc0) * fs;
        const float w1 = expf(sc1) * fs;
        const float w2 = expf(sc2) * fs;
        const float t0s = w0*w0, t1s = w1*w1, t2s = w2*w2;

        // ---- C = t0*m0 m0^T + t1*m1 m1^T + t2*m2 m2^T ----
        const float C00 = t0s*m0.x*m0.x + t1s*m1.x*m1.x + t2s*m2.x*m2.x;
        const float C01 = t0s*m0.x*m0.y + t1s*m1.x*m1.y + t2s*m2.x*m2.y;
        const float C02 = t0s*m0.x*m0.z + t1s*m1.x*m1.z + t2s*m2.x*m2.z;
        const float C11 = t0s*m0.y*m0.y + t1s*m1.y*m1.y + t2s*m2.y*m2.y;
        const float C12 = t0s*m0.y*m0.z + t1s*m1.y*m1.z + t2s*m2.y*m2.z;
        const float C22 = t0s*m0.z*m0.z + t1s*m1.z*m1.z + t2s*m2.z*m2.z;

        // ---- color ----
        const float sg = 1.0f / (1.0f + expf(-opa));
        const float c0 = fminf(fmaxf((0.5f + 0.282f*d0) * 255.0f, 0.0f), 255.0f);
        const float c1 = fminf(fmaxf((0.5f + 0.282f*d1) * 255.0f, 0.0f), 255.0f);
        const float c2 = fminf(fmaxf((0.5f + 0.282f*d2) * 255.0f, 0.0f), 255.0f);
        const float c3 = fminf(fmaxf(sg * 255.0f, 0.0f), 255.0f);

        // ---- stage row into LDS (stride 13 words: 2-way bank aliasing, free) ----
        float r[13] = {xo.x, xo.y, xo.z, c0, c1, c2, c3, C00, C01, C02, C11, C12, C22};
        #pragma unroll
        for (int j = 0; j < 13; ++j) sout[tid*13 + j] = r[j];
    }

    __syncthreads();

    // ---- coalesced float4 flush of the block's contiguous output span ----
    const int total = count * 13;
    const size_t base = (size_t)blockIdx.x * (BLK * 13);
    const int n4 = total >> 2;
    const float4* s4 = reinterpret_cast<const float4*>(sout);
    float4* o4 = reinterpret_cast<float4*>(out + base);
    for (int j = tid; j < n4; j += BLK) o4[j] = s4[j];
    for (int j = (n4 << 2) + tid; j < total; j += BLK) out[base + j] = sout[j];
}

// ---------------------------------------------------------------------------
// Fallback: fully fused (round-1) kernel, used only if ws_size is too small
// ---------------------------------------------------------------------------
__global__ __launch_bounds__(BLK) void gauss_fused_kernel(
    const float* __restrict__ verts, const int* __restrict__ faces,
    const int* __restrict__ binding, const float* __restrict__ xyz,
    const float* __restrict__ rot, const float* __restrict__ scal,
    const float* __restrict__ opac, const float* __restrict__ fdc,
    float* __restrict__ out, int N)
{
    __shared__ float sout[BLK * 13];
    const int tid = threadIdx.x;
    const int i  = blockIdx.x * BLK + tid;
    const int count = min(BLK, N - blockIdx.x * BLK);

    if (i < N) {
        const int b = binding[i];
        const int f0 = faces[3*b+0], f1 = faces[3*b+1], f2 = faces[3*b+2];
        const F3 v0 = f3(verts[3*f0], verts[3*f0+1], verts[3*f0+2]);
        const F3 v1 = f3(verts[3*f1], verts[3*f1+1], verts[3*f1+2]);
        const F3 v2 = f3(verts[3*f2], verts[3*f2+1], verts[3*f2+2]);
        const F3 fc  = mul(add(add(v0, v1), v2), (1.0f/3.0f));
        const F3 e01 = sub(v1, v0);
        const F3 e02 = sub(v2, v0);
        const F3 a0 = safe_normalize(e01);
        const F3 a1 = safe_normalize(cross3(a0, e02));
        const F3 a2 = mul(safe_normalize(cross3(a1, a0)), -1.0f);
        const float s0 = sqrtf(dot3(e01, e01));
        const float s1 = fabsf(dot3(a2, e02));
        const float fs = 0.5f * (s0 + s1);

        const float px = xyz[3*i+0], py = xyz[3*i+1], pz = xyz[3*i+2];
        const float4 q4 = reinterpret_cast<const float4*>(rot)[i];
        const float sc0 = scal[3*i+0], sc1 = scal[3*i+1], sc2 = scal[3*i+2];
        const float opa = opac[i];
        const float d0 = fdc[3*i+0], d1 = fdc[3*i+1], d2 = fdc[3*i+2];

        F3 xo = add(add(mul(a0, px), mul(a1, py)), mul(a2, pz));
        xo = add(mul(xo, fs), fc);

        const float qn = sqrtf(q4.x*q4.x + q4.y*q4.y + q4.z*q4.z + q4.w*q4.w) + 1e-12f;
        const float qinv = 1.0f / qn;
        const float w = q4.x*qinv, x = q4.y*qinv, y = q4.z*qinv, z = q4.w*qinv;
        const float Q00 = 1.0f - 2.0f*(y*y + z*z);
        const float Q01 = 2.0f*(x*y - z*w);
        const float Q02 = 2.0f*(x*z + y*w);
        const float Q10 = 2.0f*(x*y + z*w);
        const float Q11 = 1.0f - 2.0f*(x*x + z*z);
        const float Q12 = 2.0f*(y*z - x*w);
        const float Q20 = 2.0f*(x*z - y*w);
        const float Q21 = 2.0f*(y*z + x*w);
        const float Q22 = 1.0f - 2.0f*(x*x + y*y);

        const F3 m0 = add(add(mul(a0, Q00), mul(a1, Q10)), mul(a2, Q20));
        const F3 m1 = add(add(mul(a0, Q01), mul(a1, Q11)), mul(a2, Q21));
        const F3 m2 = add(add(mul(a0, Q02), mul(a1, Q12)), mul(a2, Q22));

        const float w0 = expf(sc0) * fs;
        const float w1 = expf(sc1) * fs;
        const float w2 = expf(sc2) * fs;
        const float t0 = w0*w0, t1 = w1*w1, t2 = w2*w2;

        const float C00 = t0*m0.x*m0.x + t1*m1.x*m1.x + t2*m2.x*m2.x;
        const float C01 = t0*m0.x*m0.y + t1*m1.x*m1.y + t2*m2.x*m2.y;
        const float C02 = t0*m0.x*m0.z + t1*m1.x*m1.z + t2*m2.x*m2.z;
        const float C11 = t0*m0.y*m0.y + t1*m1.y*m1.y + t2*m2.y*m2.y;
        const float C12 = t0*m0.y*m0.z + t1*m1.y*m1.z + t2*m2.y*m2.z;
        const float C22 = t0*m0.z*m0.z + t1*m1.z*m1.z + t2*m2.z*m2.z;

        const float sg = 1.0f / (1.0f + expf(-opa));
        const float c0 = fminf(fmaxf((0.5f + 0.282f*d0) * 255.0f, 0.0f), 255.0f);
        const float c1 = fminf(fmaxf((0.5f + 0.282f*d1) * 255.0f, 0.0f), 255.0f);
        const float c2 = fminf(fmaxf((0.5f + 0.282f*d2) * 255.0f, 0.0f), 255.0f);
        const float c3 = fminf(fmaxf(sg * 255.0f, 0.0f), 255.0f);

        float r[13] = {xo.x, xo.y, xo.z, c0, c1, c2, c3, C00, C01, C02, C11, C12, C22};
        #pragma unroll
        for (int j = 0; j < 13; ++j) sout[tid*13 + j] = r[j];
    }

    __syncthreads();

    const int total = count * 13;
    const size_t base = (size_t)blockIdx.x * (BLK * 13);
    const int n4 = total >> 2;
    const float4* s4 = reinterpret_cast<const float4*>(sout);
    float4* o4 = reinterpret_cast<float4*>(out + base);
    for (int j = tid; j < n4; j += BLK) o4[j] = s4[j];
    for (int j = (n4 << 2) + tid; j < total; j += BLK) out[base + j] = sout[j];
}

extern "C" void kernel_launch(void* const* d_in, const int* in_sizes, int n_in,
                              void* d_out, int out_size, void* d_ws, size_t ws_size,
                              hipStream_t stream) {
    const float* verts   = (const float*)d_in[0];
    const int*   faces   = (const int*)  d_in[1];
    const int*   binding = (const int*)  d_in[2];
    const float* xyz     = (const float*)d_in[3];
    const float* rot     = (const float*)d_in[4];
    const float* scal    = (const float*)d_in[5];
    const float* opac    = (const float*)d_in[6];
    const float* fdc     = (const float*)d_in[7];
    // d_in[8] = features_rest: unused by the reference output
    float* out = (float*)d_out;
    const int N = in_sizes[2];
    const int F = in_sizes[1] / 3;

    const size_t tab_bytes = (size_t)F * 4 * sizeof(float4);
    const int blocks = (N + BLK - 1) / BLK;

    if (ws_size >= tab_bytes) {
        float4* tab = (float4*)d_ws;
        const int fblocks = (F + BLK - 1) / BLK;
        face_precompute_kernel<<<fblocks, BLK, 0, stream>>>(verts, faces, tab, F);
        gauss_main_kernel<<<blocks, BLK, 0, stream>>>(
            tab, binding, xyz, rot, scal, opac, fdc, out, N);
    } else {
        gauss_fused_kernel<<<blocks, BLK, 0, stream>>>(
            verts, faces, binding, xyz, rot, scal, opac, fdc, out, N);
    }
}